// Round 1
// baseline (231.493 us; speedup 1.0000x reference)
//
#include <hip/hip_runtime.h>
#include <math.h>

#define DX 192
#define DY 192
#define DZ 128
#define DB 4
#define DXY (DX*DY)          // 36864
#define NTOT (DB*DZ*DXY)     // 18874368
#define XV (DX/4)            // 48 vec4 groups per row
#define NCOL (DB*DZ*XV)      // 24576 columns (b,z,xv4)
#define SEG 12               // y rows per thread
#define NSEG (DY/SEG)        // 16 segments per column

// ws layout (doubles): [0..12] sum(di*dt), [13..25] sum(dt*dt), [26] bce sum

__device__ inline float wred(float v) {
    #pragma unroll
    for (int o = 32; o > 0; o >>= 1) v += __shfl_down(v, o, 64);
    return v;
}

__device__ inline float4 ld4(const float* p) { return *(const float4*)p; }

// --- term macros -----------------------------------------------------------
// TN: unmasked term  s += di*dt ; r += dt*dt   (2 sub + 2 fma)
// TM: fx3-masked     dm = fx3*dt; s += di*dm ; r += dt*dm
#define TN(k, A1, A0, D1, D0) do { float di_=(A1)-(A0); float dt_=(D1)-(D0); \
    sk[k] += di_*dt_; rk[k] += dt_*dt_; } while(0)
#define TM(k, A1, A0, D1, D0) do { float di_=(A1)-(A0); float dt_=(D1)-(D0); \
    float dm_=fx3*dt_; sk[k] += di_*dm_; rk[k] += dt_*dm_; } while(0)
#define BCEACC(A0, D0) do { bces += (D0)*__logf(A0) + (1.0f-(D0))*__logf(1.0f-(A0)); } while(0)

// corners (z,y,x): a0=(0,0,0) a1=(0,0,1) a2=(0,1,0) a3=(0,1,1)
//                  a4=(1,0,0) a5=(1,0,1) a6=(1,1,0) a7=(1,1,1)
// offsets -> pairs: k0:(4,0) k1:(2,0) k2:(1,0) k3:(6,0) k4:(4,2) k5:(3,0)
//                   k6:(2,1) k7:(4,1) k8:(5,0) k9:(4,3) k10:(6,1) k11:(7,0) k12:(5,2)
// x-involving terms (corner 1/3/5/7): {2,5,6,7,8,9,10,11,12}

// interior element (z<127, y<191, x-neighbor valid): all 13 unmasked
#define ELEM_FULL(a0,a1,a2,a3,a4,a5,a6,a7, d0,d1,d2,d3,d4,d5,d6,d7) do { \
    TN(0,a4,a0,d4,d0); TN(1,a2,a0,d2,d0); TN(2,a1,a0,d1,d0); TN(3,a6,a0,d6,d0); \
    TN(4,a4,a2,d4,d2); TN(5,a3,a0,d3,d0); TN(6,a2,a1,d2,d1); TN(7,a4,a1,d4,d1); \
    TN(8,a5,a0,d5,d0); TN(9,a4,a3,d4,d3); TN(10,a6,a1,d6,d1); TN(11,a7,a0,d7,d0); \
    TN(12,a5,a2,d5,d2); BCEACC(a0,d0); } while(0)

// element 3 (x = x0+3): x-terms masked by fx3 (==1.0f unless this is the last vec4)
#define ELEM_FX(a0,a1,a2,a3,a4,a5,a6,a7, d0,d1,d2,d3,d4,d5,d6,d7) do { \
    TN(0,a4,a0,d4,d0); TN(1,a2,a0,d2,d0); TM(2,a1,a0,d1,d0); TN(3,a6,a0,d6,d0); \
    TN(4,a4,a2,d4,d2); TM(5,a3,a0,d3,d0); TM(6,a2,a1,d2,d1); TM(7,a4,a1,d4,d1); \
    TM(8,a5,a0,d5,d0); TM(9,a4,a3,d4,d3); TM(10,a6,a1,d6,d1); TM(11,a7,a0,d7,d0); \
    TM(12,a5,a2,d5,d2); BCEACC(a0,d0); } while(0)

// y=191 peel (z<127): only dy==0 offsets survive: k0,k2,k7,k8
#define PEL_FULL(a0,a1,a4,a5, d0,d1,d4,d5) do { \
    TN(0,a4,a0,d4,d0); TN(2,a1,a0,d1,d0); TN(7,a4,a1,d4,d1); TN(8,a5,a0,d5,d0); \
    BCEACC(a0,d0); } while(0)
#define PEL_FX(a0,a1,a4,a5, d0,d1,d4,d5) do { \
    TN(0,a4,a0,d4,d0); TM(2,a1,a0,d1,d0); TM(7,a4,a1,d4,d1); TM(8,a5,a0,d5,d0); \
    BCEACC(a0,d0); } while(0)

// z=127 body: only dz==0 offsets survive: k1,k2,k5,k6
#define ZEL_FULL(a0,a1,a2,a3, d0,d1,d2,d3) do { \
    TN(1,a2,a0,d2,d0); TN(2,a1,a0,d1,d0); TN(5,a3,a0,d3,d0); TN(6,a2,a1,d2,d1); \
    BCEACC(a0,d0); } while(0)
#define ZEL_FX(a0,a1,a2,a3, d0,d1,d2,d3) do { \
    TN(1,a2,a0,d2,d0); TM(2,a1,a0,d1,d0); TM(5,a3,a0,d3,d0); TM(6,a2,a1,d2,d1); \
    BCEACC(a0,d0); } while(0)

// z=127, y=191 peel: only k2
#define ZPEL_FULL(a0,a1, d0,d1) do { TN(2,a1,a0,d1,d0); BCEACC(a0,d0); } while(0)
#define ZPEL_FX(a0,a1, d0,d1)   do { TM(2,a1,a0,d1,d0); BCEACC(a0,d0); } while(0)

__global__ __launch_bounds__(256) void gc3d_main(const float* __restrict__ inp,
                                                 const float* __restrict__ tgt,
                                                 double* __restrict__ acc) {
    float sk[13] = {0,0,0,0,0,0,0,0,0,0,0,0,0};
    float rk[13] = {0,0,0,0,0,0,0,0,0,0,0,0,0};
    float bces = 0.f;

    // exact cover: grid = (NCOL/256, NSEG). column id c (x-vec4 fastest), segment s.
    int c   = blockIdx.x * 256 + threadIdx.x;   // [0, 24576)
    int s   = blockIdx.y;                       // [0, 16)
    int xv4 = c % XV;
    int zb  = c / XV;                           // b*DZ + z, [0, 512)
    int z   = zb & (DZ - 1);
    int y0  = s * SEG;
    bool xlast = (xv4 == XV - 1);
    int   xe   = xlast ? 3 : 4;                 // clamped x0+4 scalar offset
    float fx3  = xlast ? 0.f : 1.f;             // x-validity of element 3
    bool lastseg = (s == NSEG - 1);
    int  nfull   = SEG - (lastseg ? 1 : 0);     // 11 or 12 full-row steps

    int base = (zb * DY + y0) * DX + xv4 * 4;
    const float* ip = inp + base;
    const float* tp = tgt + base;

    if (z != DZ - 1) {
        // ---------- z-interior path ----------
        const float* ipz = ip + DXY;
        const float* tpz = tp + DXY;
        // carried row y: i0 = (y,z), i1 = (y,z+1); same for target
        float4 i0 = ld4(ip),  i1 = ld4(ipz);
        float4 t0 = ld4(tp),  t1 = ld4(tpz);
        float i0e = ip[xe],  i1e = ipz[xe];
        float t0e = tp[xe],  t1e = tpz[xe];

        for (int it = 0; it < nfull; ++it) {
            ip += DX; ipz += DX; tp += DX; tpz += DX;
            float4 j0 = ld4(ip),  j1 = ld4(ipz);      // rows y+1
            float4 u0 = ld4(tp),  u1 = ld4(tpz);
            float j0e = ip[xe],  j1e = ipz[xe];
            float u0e = tp[xe],  u1e = tpz[xe];

            // corners per element: a0,a1 from i0; a2,a3 from j0; a4,a5 from i1; a6,a7 from j1
            ELEM_FULL(i0.x,i0.y, j0.x,j0.y, i1.x,i1.y, j1.x,j1.y,
                      t0.x,t0.y, u0.x,u0.y, t1.x,t1.y, u1.x,u1.y);
            ELEM_FULL(i0.y,i0.z, j0.y,j0.z, i1.y,i1.z, j1.y,j1.z,
                      t0.y,t0.z, u0.y,u0.z, t1.y,t1.z, u1.y,u1.z);
            ELEM_FULL(i0.z,i0.w, j0.z,j0.w, i1.z,i1.w, j1.z,j1.w,
                      t0.z,t0.w, u0.z,u0.w, t1.z,t1.w, u1.z,u1.w);
            ELEM_FX  (i0.w,i0e,  j0.w,j0e,  i1.w,i1e,  j1.w,j1e,
                      t0.w,t0e,  u0.w,u0e,  t1.w,t1e,  u1.w,u1e);

            i0 = j0; i1 = j1; t0 = u0; t1 = u1;
            i0e = j0e; i1e = j1e; t0e = u0e; t1e = u1e;
        }
        if (lastseg) {
            // y = 191: rows i0 (z) and i1 (z+1) already in registers
            PEL_FULL(i0.x,i0.y, i1.x,i1.y, t0.x,t0.y, t1.x,t1.y);
            PEL_FULL(i0.y,i0.z, i1.y,i1.z, t0.y,t0.z, t1.y,t1.z);
            PEL_FULL(i0.z,i0.w, i1.z,i1.w, t0.z,t0.w, t1.z,t1.w);
            PEL_FX  (i0.w,i0e,  i1.w,i1e,  t0.w,t0e,  t1.w,t1e);
        }
    } else {
        // ---------- z = 127 path (no z+1 rows needed) ----------
        float4 i0 = ld4(ip);
        float4 t0 = ld4(tp);
        float i0e = ip[xe];
        float t0e = tp[xe];

        for (int it = 0; it < nfull; ++it) {
            ip += DX; tp += DX;
            float4 j0 = ld4(ip);
            float4 u0 = ld4(tp);
            float j0e = ip[xe];
            float u0e = tp[xe];

            ZEL_FULL(i0.x,i0.y, j0.x,j0.y, t0.x,t0.y, u0.x,u0.y);
            ZEL_FULL(i0.y,i0.z, j0.y,j0.z, t0.y,t0.z, u0.y,u0.z);
            ZEL_FULL(i0.z,i0.w, j0.z,j0.w, t0.z,t0.w, u0.z,u0.w);
            ZEL_FX  (i0.w,i0e,  j0.w,j0e,  t0.w,t0e,  u0.w,u0e);

            i0 = j0; t0 = u0; i0e = j0e; t0e = u0e;
        }
        if (lastseg) {
            ZPEL_FULL(i0.x,i0.y, t0.x,t0.y);
            ZPEL_FULL(i0.y,i0.z, t0.y,t0.z);
            ZPEL_FULL(i0.z,i0.w, t0.z,t0.w);
            ZPEL_FX  (i0.w,i0e,  t0.w,t0e);
        }
    }

    // block reduction: wave shuffle -> LDS -> 27 double atomics
    float vals[27];
    #pragma unroll
    for (int q = 0; q < 13; q++) { vals[q] = sk[q]; vals[13 + q] = rk[q]; }
    vals[26] = bces;
    #pragma unroll
    for (int q = 0; q < 27; q++) vals[q] = wred(vals[q]);

    __shared__ float red[4][27];
    int lane = threadIdx.x & 63;
    int wave = threadIdx.x >> 6;
    if (lane == 0) {
        #pragma unroll
        for (int q = 0; q < 27; q++) red[wave][q] = vals[q];
    }
    __syncthreads();
    if (threadIdx.x < 27) {
        float t = red[0][threadIdx.x] + red[1][threadIdx.x]
                + red[2][threadIdx.x] + red[3][threadIdx.x];
        atomicAdd(&acc[threadIdx.x], (double)t);
    }
}

__global__ void gc3d_final(const double* __restrict__ acc, float* __restrict__ out) {
    if (threadIdx.x == 0 && blockIdx.x == 0) {
        double s = 0.0;
        #pragma unroll
        for (int k = 0; k < 13; k++) s += acc[k] / (acc[13 + k] + 1e-5);
        double bce = -acc[26] / (double)NTOT;
        out[0] = (float)(bce + 1.0 - s / 13.0);
    }
}

extern "C" void kernel_launch(void* const* d_in, const int* in_sizes, int n_in,
                              void* d_out, int out_size, void* d_ws, size_t ws_size,
                              hipStream_t stream) {
    const float* inp = (const float*)d_in[0];
    const float* tgt = (const float*)d_in[1];
    double* acc = (double*)d_ws;

    hipMemsetAsync(d_ws, 0, 27 * sizeof(double), stream);
    dim3 grid(NCOL / 256, NSEG);
    gc3d_main<<<grid, 256, 0, stream>>>(inp, tgt, acc);
    gc3d_final<<<1, 64, 0, stream>>>(acc, (float*)d_out);
}

// Round 2
// 214.466 us; speedup vs baseline: 1.0794x; 1.0794x over previous
//
#include <hip/hip_runtime.h>
#include <math.h>

#define DX 192
#define DY 192
#define DZ 128
#define DB 4
#define DXY (DX*DY)          // 36864
#define NTOT (DB*DZ*DXY)     // 18874368
#define XV (DX/4)            // 48 vec4 groups per row
#define NCOL (DB*DZ*XV)      // 24576 columns (b,z,xv4)
#define SEG 12               // y rows per thread
#define NSEG (DY/SEG)        // 16 segments per column

// ws layout (doubles): [0..12] sum(di*dt), [13..25] sum(dt*dt), [26] bce sum

__device__ inline float wred(float v) {
    #pragma unroll
    for (int o = 32; o > 0; o >>= 1) v += __shfl_down(v, o, 64);
    return v;
}

__device__ inline float4 ld4(const float* p) { return *(const float4*)p; }

// --- term macros -----------------------------------------------------------
#define TN(k, A1, A0, D1, D0) do { float di_=(A1)-(A0); float dt_=(D1)-(D0); \
    sk[k] += di_*dt_; rk[k] += dt_*dt_; } while(0)
#define TM(k, A1, A0, D1, D0) do { float di_=(A1)-(A0); float dt_=(D1)-(D0); \
    float dm_=fx3*dt_; sk[k] += di_*dm_; rk[k] += dt_*dm_; } while(0)
#define BCEACC(A0, D0) do { bces += (D0)*__logf(A0) + (1.0f-(D0))*__logf(1.0f-(A0)); } while(0)

// corners (z,y,x): a0=(0,0,0) a1=(0,0,1) a2=(0,1,0) a3=(0,1,1)
//                  a4=(1,0,0) a5=(1,0,1) a6=(1,1,0) a7=(1,1,1)
// offsets -> pairs: k0:(4,0) k1:(2,0) k2:(1,0) k3:(6,0) k4:(4,2) k5:(3,0)
//                   k6:(2,1) k7:(4,1) k8:(5,0) k9:(4,3) k10:(6,1) k11:(7,0) k12:(5,2)

#define ELEM_FULL(a0,a1,a2,a3,a4,a5,a6,a7, d0,d1,d2,d3,d4,d5,d6,d7) do { \
    TN(0,a4,a0,d4,d0); TN(1,a2,a0,d2,d0); TN(2,a1,a0,d1,d0); TN(3,a6,a0,d6,d0); \
    TN(4,a4,a2,d4,d2); TN(5,a3,a0,d3,d0); TN(6,a2,a1,d2,d1); TN(7,a4,a1,d4,d1); \
    TN(8,a5,a0,d5,d0); TN(9,a4,a3,d4,d3); TN(10,a6,a1,d6,d1); TN(11,a7,a0,d7,d0); \
    TN(12,a5,a2,d5,d2); BCEACC(a0,d0); } while(0)

#define ELEM_FX(a0,a1,a2,a3,a4,a5,a6,a7, d0,d1,d2,d3,d4,d5,d6,d7) do { \
    TN(0,a4,a0,d4,d0); TN(1,a2,a0,d2,d0); TM(2,a1,a0,d1,d0); TN(3,a6,a0,d6,d0); \
    TN(4,a4,a2,d4,d2); TM(5,a3,a0,d3,d0); TM(6,a2,a1,d2,d1); TM(7,a4,a1,d4,d1); \
    TM(8,a5,a0,d5,d0); TM(9,a4,a3,d4,d3); TM(10,a6,a1,d6,d1); TM(11,a7,a0,d7,d0); \
    TM(12,a5,a2,d5,d2); BCEACC(a0,d0); } while(0)

// y=191 peel (z<127): only dy==0 offsets survive: k0,k2,k7,k8
#define PEL_FULL(a0,a1,a4,a5, d0,d1,d4,d5) do { \
    TN(0,a4,a0,d4,d0); TN(2,a1,a0,d1,d0); TN(7,a4,a1,d4,d1); TN(8,a5,a0,d5,d0); \
    BCEACC(a0,d0); } while(0)
#define PEL_FX(a0,a1,a4,a5, d0,d1,d4,d5) do { \
    TN(0,a4,a0,d4,d0); TM(2,a1,a0,d1,d0); TM(7,a4,a1,d4,d1); TM(8,a5,a0,d5,d0); \
    BCEACC(a0,d0); } while(0)

// z=127 body: only dz==0 offsets survive: k1,k2,k5,k6
#define ZEL_FULL(a0,a1,a2,a3, d0,d1,d2,d3) do { \
    TN(1,a2,a0,d2,d0); TN(2,a1,a0,d1,d0); TN(5,a3,a0,d3,d0); TN(6,a2,a1,d2,d1); \
    BCEACC(a0,d0); } while(0)
#define ZEL_FX(a0,a1,a2,a3, d0,d1,d2,d3) do { \
    TN(1,a2,a0,d2,d0); TM(2,a1,a0,d1,d0); TM(5,a3,a0,d3,d0); TM(6,a2,a1,d2,d1); \
    BCEACC(a0,d0); } while(0)

// z=127, y=191 peel: only k2
#define ZPEL_FULL(a0,a1, d0,d1) do { TN(2,a1,a0,d1,d0); BCEACC(a0,d0); } while(0)
#define ZPEL_FX(a0,a1, d0,d1)   do { TM(2,a1,a0,d1,d0); BCEACC(a0,d0); } while(0)

// compute the 4 elements of a vec4 group from rows A (y) and B (y+1)
#define ROW_FULL(Ai0,Ai1,Aie, At0,At1,Ate, Bi0,Bi1,Bie, Bt0,Bt1,Bte) do { \
    ELEM_FULL(Ai0.x,Ai0.y, Bi0.x,Bi0.y, Ai1.x,Ai1.y, Bi1.x,Bi1.y, \
              At0.x,At0.y, Bt0.x,Bt0.y, At1.x,At1.y, Bt1.x,Bt1.y); \
    ELEM_FULL(Ai0.y,Ai0.z, Bi0.y,Bi0.z, Ai1.y,Ai1.z, Bi1.y,Bi1.z, \
              At0.y,At0.z, Bt0.y,Bt0.z, At1.y,At1.z, Bt1.y,Bt1.z); \
    ELEM_FULL(Ai0.z,Ai0.w, Bi0.z,Bi0.w, Ai1.z,Ai1.w, Bi1.z,Bi1.w, \
              At0.z,At0.w, Bt0.z,Bt0.w, At1.z,At1.w, Bt1.z,Bt1.w); \
    ELEM_FX  (Ai0.w,Aie,   Bi0.w,Bie,   Ai1.w,Ai1##e_, Bi1.w,Bi1##e_, \
              At0.w,Ate,   Bt0.w,Bte,   At1.w,At1##e_, Bt1.w,Bt1##e_); \
    } while(0)

__global__ __launch_bounds__(256) void gc3d_main(const float* __restrict__ inp,
                                                 const float* __restrict__ tgt,
                                                 double* __restrict__ acc) {
    float sk[13] = {0,0,0,0,0,0,0,0,0,0,0,0,0};
    float rk[13] = {0,0,0,0,0,0,0,0,0,0,0,0,0};
    float bces = 0.f;

    int c   = blockIdx.x * 256 + threadIdx.x;   // [0, 24576)
    int s   = blockIdx.y;                       // [0, 16)
    int xv4 = c % XV;
    int zb  = c / XV;                           // b*DZ + z, [0, 512)
    int z   = zb & (DZ - 1);
    int y0  = s * SEG;
    bool xlast = (xv4 == XV - 1);
    int   xe   = xlast ? 3 : 4;
    float fx3  = xlast ? 0.f : 1.f;
    bool lastseg = (s == NSEG - 1);
    int  nfull   = SEG - (lastseg ? 1 : 0);     // 11 or 12 computed rows

    int base = (zb * DY + y0) * DX + xv4 * 4;
    const float* ip = inp + base;
    const float* tp = tgt + base;

    if (z != DZ - 1) {
        // ---------- z-interior path, 1-deep software pipeline ----------
        // i-set: rows (y,z)/(y,z+1); j-set: rows (y+1, .); k-set: prefetch (y+2, .)
        float4 i0 = ld4(ip),        i1 = ld4(ip + DXY);
        float4 t0 = ld4(tp),        t1 = ld4(tp + DXY);
        float  i0e = ip[xe],        i1e = ip[DXY + xe];
        float  t0e = tp[xe],        t1e = tp[DXY + xe];
        float4 j0 = ld4(ip + DX),   j1 = ld4(ip + DX + DXY);
        float4 u0 = ld4(tp + DX),   u1 = ld4(tp + DX + DXY);
        float  j0e = ip[DX + xe],   j1e = ip[DX + DXY + xe];
        float  u0e = tp[DX + xe],   u1e = tp[DX + DXY + xe];

        #pragma unroll 2
        for (int it = 0; it < nfull - 1; ++it) {
            // prefetch rows y+2 (never OOB: max prefetched row index is 191)
            const float* ipk = ip + 2 * DX;
            const float* tpk = tp + 2 * DX;
            float4 k0 = ld4(ipk),       k1 = ld4(ipk + DXY);
            float4 w0 = ld4(tpk),       w1 = ld4(tpk + DXY);
            float  k0e = ipk[xe],       k1e = ipk[DXY + xe];
            float  w0e = tpk[xe],       w1e = tpk[DXY + xe];

            // compute on resident rows y (i-set) and y+1 (j-set)
            ELEM_FULL(i0.x,i0.y, j0.x,j0.y, i1.x,i1.y, j1.x,j1.y,
                      t0.x,t0.y, u0.x,u0.y, t1.x,t1.y, u1.x,u1.y);
            ELEM_FULL(i0.y,i0.z, j0.y,j0.z, i1.y,i1.z, j1.y,j1.z,
                      t0.y,t0.z, u0.y,u0.z, t1.y,t1.z, u1.y,u1.z);
            ELEM_FULL(i0.z,i0.w, j0.z,j0.w, i1.z,i1.w, j1.z,j1.w,
                      t0.z,t0.w, u0.z,u0.w, t1.z,t1.w, u1.z,u1.w);
            ELEM_FX  (i0.w,i0e,  j0.w,j0e,  i1.w,i1e,  j1.w,j1e,
                      t0.w,t0e,  u0.w,u0e,  t1.w,t1e,  u1.w,u1e);

            // rotate: i <- j, j <- k
            i0 = j0; i1 = j1; t0 = u0; t1 = u1;
            i0e = j0e; i1e = j1e; t0e = u0e; t1e = u1e;
            j0 = k0; j1 = k1; u0 = w0; u1 = w1;
            j0e = k0e; j1e = k1e; u0e = w0e; u1e = w1e;
            ip += DX; tp += DX;
        }
        // final full row (no prefetch)
        ELEM_FULL(i0.x,i0.y, j0.x,j0.y, i1.x,i1.y, j1.x,j1.y,
                  t0.x,t0.y, u0.x,u0.y, t1.x,t1.y, u1.x,u1.y);
        ELEM_FULL(i0.y,i0.z, j0.y,j0.z, i1.y,i1.z, j1.y,j1.z,
                  t0.y,t0.z, u0.y,u0.z, t1.y,t1.z, u1.y,u1.z);
        ELEM_FULL(i0.z,i0.w, j0.z,j0.w, i1.z,i1.w, j1.z,j1.w,
                  t0.z,t0.w, u0.z,u0.w, t1.z,t1.w, u1.z,u1.w);
        ELEM_FX  (i0.w,i0e,  j0.w,j0e,  i1.w,i1e,  j1.w,j1e,
                  t0.w,t0e,  u0.w,u0e,  t1.w,t1e,  u1.w,u1e);

        if (lastseg) {
            // y = 191 lives in the j-set after the final compute
            PEL_FULL(j0.x,j0.y, j1.x,j1.y, u0.x,u0.y, u1.x,u1.y);
            PEL_FULL(j0.y,j0.z, j1.y,j1.z, u0.y,u0.z, u1.y,u1.z);
            PEL_FULL(j0.z,j0.w, j1.z,j1.w, u0.z,u0.w, u1.z,u1.w);
            PEL_FX  (j0.w,j0e,  j1.w,j1e,  u0.w,u0e,  u1.w,u1e);
        }
    } else {
        // ---------- z = 127 path ----------
        float4 i0 = ld4(ip);
        float4 t0 = ld4(tp);
        float  i0e = ip[xe];
        float  t0e = tp[xe];
        float4 j0 = ld4(ip + DX);
        float4 u0 = ld4(tp + DX);
        float  j0e = ip[DX + xe];
        float  u0e = tp[DX + xe];

        #pragma unroll 2
        for (int it = 0; it < nfull - 1; ++it) {
            const float* ipk = ip + 2 * DX;
            const float* tpk = tp + 2 * DX;
            float4 k0 = ld4(ipk);
            float4 w0 = ld4(tpk);
            float  k0e = ipk[xe];
            float  w0e = tpk[xe];

            ZEL_FULL(i0.x,i0.y, j0.x,j0.y, t0.x,t0.y, u0.x,u0.y);
            ZEL_FULL(i0.y,i0.z, j0.y,j0.z, t0.y,t0.z, u0.y,u0.z);
            ZEL_FULL(i0.z,i0.w, j0.z,j0.w, t0.z,t0.w, u0.z,u0.w);
            ZEL_FX  (i0.w,i0e,  j0.w,j0e,  t0.w,t0e,  u0.w,u0e);

            i0 = j0; t0 = u0; i0e = j0e; t0e = u0e;
            j0 = k0; u0 = w0; j0e = k0e; u0e = w0e;
            ip += DX; tp += DX;
        }
        ZEL_FULL(i0.x,i0.y, j0.x,j0.y, t0.x,t0.y, u0.x,u0.y);
        ZEL_FULL(i0.y,i0.z, j0.y,j0.z, t0.y,t0.z, u0.y,u0.z);
        ZEL_FULL(i0.z,i0.w, j0.z,j0.w, t0.z,t0.w, u0.z,u0.w);
        ZEL_FX  (i0.w,i0e,  j0.w,j0e,  t0.w,t0e,  u0.w,u0e);

        if (lastseg) {
            ZPEL_FULL(j0.x,j0.y, u0.x,u0.y);
            ZPEL_FULL(j0.y,j0.z, u0.y,u0.z);
            ZPEL_FULL(j0.z,j0.w, u0.z,u0.w);
            ZPEL_FX  (j0.w,j0e,  u0.w,u0e);
        }
    }

    // block reduction: wave shuffle -> LDS -> 27 double atomics
    float vals[27];
    #pragma unroll
    for (int q = 0; q < 13; q++) { vals[q] = sk[q]; vals[13 + q] = rk[q]; }
    vals[26] = bces;
    #pragma unroll
    for (int q = 0; q < 27; q++) vals[q] = wred(vals[q]);

    __shared__ float red[4][27];
    int lane = threadIdx.x & 63;
    int wave = threadIdx.x >> 6;
    if (lane == 0) {
        #pragma unroll
        for (int q = 0; q < 27; q++) red[wave][q] = vals[q];
    }
    __syncthreads();
    if (threadIdx.x < 27) {
        float t = red[0][threadIdx.x] + red[1][threadIdx.x]
                + red[2][threadIdx.x] + red[3][threadIdx.x];
        atomicAdd(&acc[threadIdx.x], (double)t);
    }
}

__global__ void gc3d_final(const double* __restrict__ acc, float* __restrict__ out) {
    if (threadIdx.x == 0 && blockIdx.x == 0) {
        double s = 0.0;
        #pragma unroll
        for (int k = 0; k < 13; k++) s += acc[k] / (acc[13 + k] + 1e-5);
        double bce = -acc[26] / (double)NTOT;
        out[0] = (float)(bce + 1.0 - s / 13.0);
    }
}

extern "C" void kernel_launch(void* const* d_in, const int* in_sizes, int n_in,
                              void* d_out, int out_size, void* d_ws, size_t ws_size,
                              hipStream_t stream) {
    const float* inp = (const float*)d_in[0];
    const float* tgt = (const float*)d_in[1];
    double* acc = (double*)d_ws;

    hipMemsetAsync(d_ws, 0, 27 * sizeof(double), stream);
    dim3 grid(NCOL / 256, NSEG);
    gc3d_main<<<grid, 256, 0, stream>>>(inp, tgt, acc);
    gc3d_final<<<1, 64, 0, stream>>>(acc, (float*)d_out);
}